// Round 6
// baseline (73.262 us; speedup 1.0000x reference)
//
#include <hip/hip_runtime.h>
#include <math.h>

// Banded self-attention, fp32. B=4, T=4096, D=64, MASK_NUM=64.
// One 64-lane wave handles FOUR consecutive query rows (t0..t0+3); each K/V
// row load feeds four dots. 8 subgroups of 8 lanes; subgroup g handles key
// slots s = s_lo+g+8i. Lane r of a subgroup owns dims [8r, 8r+8).
// Online softmax with THRESHOLD-DEFERRED max (T13): m starts at -20 and is
// only raised when a score exceeds m+8 (wave-uniform __any branch, fires
// ~1-2x per wave total). Weights bounded by e^8 -> fp32-safe; the merge
// applies the true max, so results are exact.
// Depth-2 software pipeline: 3 rotating register buffer sets for K+V,
// statically indexed (fully unrolled loop, i%3 folds to constants).
// 1-wave blocks; __launch_bounds__(64,3) caps VGPR for 3 waves/SIMD.

constexpr int   kB = 4;
constexpr int   kT = 4096;
constexpr int   kD = 64;
constexpr int   kBand  = 64;   // MASK_NUM
constexpr int   kQ     = 4;    // queries per wave
constexpr int   kIters = 17;   // ceil((2*kBand + kQ)/8)
constexpr float kThr   = 8.0f; // deferred-max threshold
constexpr float kInitM = -20.0f;

__device__ __forceinline__ float sum8_dpp(float x) {
    // all-lanes sum within each 8-lane group:
    // quad_perm xor1 (0xB1), quad_perm xor2 (0x4E), row_half_mirror (0x141)
    int v = __float_as_int(x);
    x += __int_as_float(__builtin_amdgcn_update_dpp(0, v, 0xB1, 0xF, 0xF, true));
    v = __float_as_int(x);
    x += __int_as_float(__builtin_amdgcn_update_dpp(0, v, 0x4E, 0xF, 0xF, true));
    v = __float_as_int(x);
    x += __int_as_float(__builtin_amdgcn_update_dpp(0, v, 0x141, 0xF, 0xF, true));
    return x;
}

__global__ __launch_bounds__(64, 3) void band_attn_kernel(
    const float* __restrict__ Q,
    const float* __restrict__ K,
    const float* __restrict__ V,
    const int*   __restrict__ M,
    float* __restrict__ O)
{
    const int lane = threadIdx.x & 63;
    const int gw   = blockIdx.x;                   // one wave per block
    if (gw >= (kB * kT) / kQ) return;
    const int b  = gw >> 10;                       // 1024 waves per batch
    const int t0 = (gw & 1023) << 2;               // first of 4 queries
    const int row0 = b * kT + t0;

    const int g = lane >> 3;   // subgroup 0..7 (key slot)
    const int r = lane & 7;    // dims 8r..8r+7

    // load + pre-scale the four query rows (each lane: dims 8r..8r+7)
    float4 q[kQ][2];
    #pragma unroll
    for (int j = 0; j < kQ; ++j) {
        const float* qr = Q + (size_t)(row0 + j) * kD + 8 * r;
        q[j][0] = *reinterpret_cast<const float4*>(qr);
        q[j][1] = *reinterpret_cast<const float4*>(qr + 4);
        q[j][0].x *= 0.125f; q[j][0].y *= 0.125f; q[j][0].z *= 0.125f; q[j][0].w *= 0.125f;
        q[j][1].x *= 0.125f; q[j][1].y *= 0.125f; q[j][1].z *= 0.125f; q[j][1].w *= 0.125f;
    }

    const float* kb = K + (size_t)b * kT * kD;
    const float* vb = V + (size_t)b * kT * kD;
    const int*   mb = M + b * kT;

    const bool allq = mb[t0] && mb[t0 + 1] && mb[t0 + 2] && mb[t0 + 3];

    if (allq) {
        // -------- fast path: all four queries banded --------
        int s_lo = t0 - kBand;            if (s_lo < 0) s_lo = 0;
        int s_hi = t0 + (kQ - 1) + kBand; if (s_hi > kT - 1) s_hi = kT - 1;
        const int s0 = s_lo + g;
        const int e0 = s0 - t0 + kBand;   // band coordinate of slot i=0

        // key-mask bits, one per slot
        unsigned mv = 0u;
        #pragma unroll
        for (int i = 0; i < kIters; ++i) {
            const int s  = s0 + 8 * i;
            const int sc = (s <= s_hi) ? s : s_hi;
            mv |= (mb[sc] ? 1u : 0u) << i;
        }

        // online-softmax state (statically indexed only)
        float  m_[kQ] = {kInitM, kInitM, kInitM, kInitM};
        float  l_[kQ] = {0.f, 0.f, 0.f, 0.f};
        float4 a_[kQ][2];
        #pragma unroll
        for (int j = 0; j < kQ; ++j) {
            a_[j][0] = make_float4(0.f, 0.f, 0.f, 0.f);
            a_[j][1] = make_float4(0.f, 0.f, 0.f, 0.f);
        }

        // 3 rotating K/V buffer sets (depth-2 prefetch)
        float4 kb0[3], kb1[3], vb0[3], vb1[3];

        #define LOADKV(S, I) do {                                             \
            const int s_  = s0 + 8 * (I);                                     \
            const int sc_ = (s_ <= s_hi) ? s_ : s_hi;                         \
            const float* kr_ = kb + (size_t)sc_ * kD + 8 * r;                 \
            const float* vr_ = vb + (size_t)sc_ * kD + 8 * r;                 \
            kb0[(S)] = *reinterpret_cast<const float4*>(kr_);                 \
            kb1[(S)] = *reinterpret_cast<const float4*>(kr_ + 4);             \
            vb0[(S)] = *reinterpret_cast<const float4*>(vr_);                 \
            vb1[(S)] = *reinterpret_cast<const float4*>(vr_ + 4);             \
        } while (0)

        LOADKV(0, 0);
        LOADKV(1, 1);

        #pragma unroll
        for (int i = 0; i < kIters; ++i) {
            const int sl = i % 3;
            if (i + 2 < kIters) {
                LOADKV((i + 2) % 3, i + 2);       // depth-2 prefetch
            }

            const int  s  = s0 + 8 * i;
            const bool ok = (s <= s_hi) && ((mv >> i) & 1u);
            const int  e  = e0 + 8 * i;           // s - t0 + kBand

            // scores for the 4 queries against this subgroup's key
            float dv[kQ];
            #pragma unroll
            for (int j = 0; j < kQ; ++j) {
                float d = q[j][0].x * kb0[sl].x + q[j][0].y * kb0[sl].y
                        + q[j][0].z * kb0[sl].z + q[j][0].w * kb0[sl].w
                        + q[j][1].x * kb1[sl].x + q[j][1].y * kb1[sl].y
                        + q[j][1].z * kb1[sl].z + q[j][1].w * kb1[sl].w;
                d = sum8_dpp(d);
                const bool band = (unsigned)(e - j) <= (unsigned)(2 * kBand);
                dv[j] = (ok && band) ? d : -1e30f;   // exp(-1e30-m) -> 0
            }

            // deferred-max: rescale only when a score exceeds m+thr (rare)
            const bool need = (dv[0] > m_[0] + kThr) | (dv[1] > m_[1] + kThr)
                            | (dv[2] > m_[2] + kThr) | (dv[3] > m_[3] + kThr);
            if (__any(need)) {
                #pragma unroll
                for (int j = 0; j < kQ; ++j) {
                    const float nm  = fmaxf(m_[j], dv[j]);
                    const float scl = __expf(m_[j] - nm);   // ==1 if unchanged
                    l_[j] *= scl;
                    a_[j][0].x *= scl; a_[j][0].y *= scl;
                    a_[j][0].z *= scl; a_[j][0].w *= scl;
                    a_[j][1].x *= scl; a_[j][1].y *= scl;
                    a_[j][1].z *= scl; a_[j][1].w *= scl;
                    m_[j] = nm;
                }
            }

            // weights + PV accumulate
            #pragma unroll
            for (int j = 0; j < kQ; ++j) {
                const float w = __expf(dv[j] - m_[j]);  // bounded by e^thr
                l_[j] += w;
                a_[j][0].x += w * vb0[sl].x; a_[j][0].y += w * vb0[sl].y;
                a_[j][0].z += w * vb0[sl].z; a_[j][0].w += w * vb0[sl].w;
                a_[j][1].x += w * vb1[sl].x; a_[j][1].y += w * vb1[sl].y;
                a_[j][1].z += w * vb1[sl].z; a_[j][1].w += w * vb1[sl].w;
            }
        }
        #undef LOADKV

        // ---- merge the 8 subgroup states ----
        // 1) true global max per query, 2) rescale local state once, 3) sum
        #pragma unroll
        for (int j = 0; j < kQ; ++j) {
            float Mx = m_[j];
            Mx = fmaxf(Mx, __shfl_xor(Mx, 8, 64));
            Mx = fmaxf(Mx, __shfl_xor(Mx, 16, 64));
            Mx = fmaxf(Mx, __shfl_xor(Mx, 32, 64));
            const float scl = __expf(m_[j] - Mx);
            l_[j] *= scl;
            a_[j][0].x *= scl; a_[j][0].y *= scl;
            a_[j][0].z *= scl; a_[j][0].w *= scl;
            a_[j][1].x *= scl; a_[j][1].y *= scl;
            a_[j][1].z *= scl; a_[j][1].w *= scl;
        }
        #pragma unroll
        for (int off = 8; off <= 32; off <<= 1) {
            #pragma unroll
            for (int j = 0; j < kQ; ++j) {
                l_[j] += __shfl_xor(l_[j], off, 64);
                a_[j][0].x += __shfl_xor(a_[j][0].x, off, 64);
                a_[j][0].y += __shfl_xor(a_[j][0].y, off, 64);
                a_[j][0].z += __shfl_xor(a_[j][0].z, off, 64);
                a_[j][0].w += __shfl_xor(a_[j][0].w, off, 64);
                a_[j][1].x += __shfl_xor(a_[j][1].x, off, 64);
                a_[j][1].y += __shfl_xor(a_[j][1].y, off, 64);
                a_[j][1].z += __shfl_xor(a_[j][1].z, off, 64);
                a_[j][1].w += __shfl_xor(a_[j][1].w, off, 64);
            }
        }

        // output: subgroup J writes query J (compile-time indices only)
        #define WRITE_OUT(J)                                                  \
            if (g == (J)) {                                                   \
                const float inv = 1.0f / l_[(J)];                             \
                float* orow = O + (size_t)(row0 + (J)) * kD + 8 * r;          \
                float4 o0, o1;                                                \
                o0.x = a_[(J)][0].x * inv; o0.y = a_[(J)][0].y * inv;         \
                o0.z = a_[(J)][0].z * inv; o0.w = a_[(J)][0].w * inv;         \
                o1.x = a_[(J)][1].x * inv; o1.y = a_[(J)][1].y * inv;         \
                o1.z = a_[(J)][1].z * inv; o1.w = a_[(J)][1].w * inv;         \
                *reinterpret_cast<float4*>(orow)     = o0;                    \
                *reinterpret_cast<float4*>(orow + 4) = o1;                    \
            }
        WRITE_OUT(0)
        WRITE_OUT(1)
        WRITE_OUT(2)
        WRITE_OUT(3)
        #undef WRITE_OUT
        return;
    }

    // -------- generic fallback (not hit by the bench mask) --------
    // fully unrolled so q[qq] stays statically indexed (no scratch)
    #pragma unroll
    for (int qq = 0; qq < kQ; ++qq) {
        const int t  = t0 + qq;
        const int qm = mb[t];
        const float4 q0 = q[qq][0];
        const float4 q1 = q[qq][1];
        int lo, hi;
        if (qm) {
            lo = t - kBand; if (lo < 0) lo = 0;
            hi = t + kBand; if (hi > kT - 1) hi = kT - 1;
        } else {
            lo = 0; hi = kT - 1;
        }
        float m = -INFINITY, l = 0.f;
        float4 acc0 = make_float4(0.f,0.f,0.f,0.f), acc1 = acc0;
        for (int s = lo + g; s <= hi; s += 8) {
            const float* kr = kb + (size_t)s * kD + 8 * r;
            const float4 k0 = *reinterpret_cast<const float4*>(kr);
            const float4 k1 = *reinterpret_cast<const float4*>(kr + 4);
            float d = q0.x * k0.x + q0.y * k0.y + q0.z * k0.z + q0.w * k0.w
                    + q1.x * k1.x + q1.y * k1.y + q1.z * k1.z + q1.w * k1.w;
            d = sum8_dpp(d);
            if (mb[s]) {
                if (d > m) {
                    const float scl = __expf(m - d);
                    l *= scl;
                    acc0.x *= scl; acc0.y *= scl; acc0.z *= scl; acc0.w *= scl;
                    acc1.x *= scl; acc1.y *= scl; acc1.z *= scl; acc1.w *= scl;
                    m = d;
                }
                const float w = __expf(d - m);
                const float* vr = vb + (size_t)s * kD + 8 * r;
                const float4 v0 = *reinterpret_cast<const float4*>(vr);
                const float4 v1 = *reinterpret_cast<const float4*>(vr + 4);
                l += w;
                acc0.x += w * v0.x; acc0.y += w * v0.y;
                acc0.z += w * v0.z; acc0.w += w * v0.w;
                acc1.x += w * v1.x; acc1.y += w * v1.y;
                acc1.z += w * v1.z; acc1.w += w * v1.w;
            }
        }
        // merge: max, rescale once, sum
        float Mx = m;
        Mx = fmaxf(Mx, __shfl_xor(Mx, 8, 64));
        Mx = fmaxf(Mx, __shfl_xor(Mx, 16, 64));
        Mx = fmaxf(Mx, __shfl_xor(Mx, 32, 64));
        const float scl = __expf(m - Mx);
        l *= scl;
        acc0.x *= scl; acc0.y *= scl; acc0.z *= scl; acc0.w *= scl;
        acc1.x *= scl; acc1.y *= scl; acc1.z *= scl; acc1.w *= scl;
        #pragma unroll
        for (int off = 8; off <= 32; off <<= 1) {
            l += __shfl_xor(l, off, 64);
            acc0.x += __shfl_xor(acc0.x, off, 64);
            acc0.y += __shfl_xor(acc0.y, off, 64);
            acc0.z += __shfl_xor(acc0.z, off, 64);
            acc0.w += __shfl_xor(acc0.w, off, 64);
            acc1.x += __shfl_xor(acc1.x, off, 64);
            acc1.y += __shfl_xor(acc1.y, off, 64);
            acc1.z += __shfl_xor(acc1.z, off, 64);
            acc1.w += __shfl_xor(acc1.w, off, 64);
        }
        if (g == 0) {
            const float inv = 1.0f / l;
            float* orow = O + (size_t)(b * kT + t) * kD + 8 * r;
            float4 o0, o1;
            o0.x = acc0.x * inv; o0.y = acc0.y * inv;
            o0.z = acc0.z * inv; o0.w = acc0.w * inv;
            o1.x = acc1.x * inv; o1.y = acc1.y * inv;
            o1.z = acc1.z * inv; o1.w = acc1.w * inv;
            *reinterpret_cast<float4*>(orow)     = o0;
            *reinterpret_cast<float4*>(orow + 4) = o1;
        }
    }
}

extern "C" void kernel_launch(void* const* d_in, const int* in_sizes, int n_in,
                              void* d_out, int out_size, void* d_ws, size_t ws_size,
                              hipStream_t stream) {
    const float* q    = (const float*)d_in[0];
    const float* k    = (const float*)d_in[1];
    const float* v    = (const float*)d_in[2];
    const int*   mask = (const int*)d_in[3];
    float*       out  = (float*)d_out;

    const int waves = (kB * kT) / kQ;         // 4096 waves
    dim3 grid(waves);                         // one wave per block
    dim3 block(64);
    band_attn_kernel<<<grid, block, 0, stream>>>(q, k, v, mask, out);
}

// Round 7
// 72.163 us; speedup vs baseline: 1.0152x; 1.0152x over previous
//
#include <hip/hip_runtime.h>
#include <math.h>

// Banded self-attention, fp32. B=4, T=4096, D=64, MASK_NUM=64.
// Block = 256 threads = 4 waves = 16 consecutive queries (4 per wave).
// The 16 queries' union band is 144 K/V rows; it is staged into LDS in
// TWO passes of 72 rows (K[72][68] + V[72][68], 38.25 KB -> 4 blocks/CU,
// fits the 64 KB static-LDS limit). Each wave then runs the proven
// subgroup-DPP online-softmax core (R5) reading from LDS:
//   8 subgroups of 8 lanes; subgroup g handles band slots u = lo_u+g+8i;
//   lane r owns dims [8r, 8r+8). Row pad = 68 floats keeps every float4
//   16B-aligned and spreads banks at the b128 structural minimum.
// Deferred-max online softmax (T13): m starts at 0, rescale only when a
// score exceeds m+8 (never fires on N(0,1) data; correct in general since
// the merge normalizes against a common reference).
// Register state is deliberately tiny (R4/R6 lesson: spills killed both).

constexpr int   kB     = 4;
constexpr int   kT     = 4096;
constexpr int   kD     = 64;
constexpr int   kBand  = 64;    // MASK_NUM
constexpr int   kQ     = 4;     // queries per wave
constexpr int   kQB    = 16;    // queries per block
constexpr int   kRowsP = 72;    // tile rows per pass (2 passes = 144)
constexpr int   kPad   = 68;    // floats per padded row (272 B, 16B-aligned)
constexpr int   kVOff  = kRowsP * kPad;   // V region offset in floats
constexpr float kThr   = 8.0f;  // deferred-max threshold
constexpr float kInitM = 0.0f;

__device__ __forceinline__ float sum8_dpp(float x) {
    // all-lanes sum within each 8-lane group:
    // quad_perm xor1 (0xB1), quad_perm xor2 (0x4E), row_half_mirror (0x141)
    int v = __float_as_int(x);
    x += __int_as_float(__builtin_amdgcn_update_dpp(0, v, 0xB1, 0xF, 0xF, true));
    v = __float_as_int(x);
    x += __int_as_float(__builtin_amdgcn_update_dpp(0, v, 0x4E, 0xF, 0xF, true));
    v = __float_as_int(x);
    x += __int_as_float(__builtin_amdgcn_update_dpp(0, v, 0x141, 0xF, 0xF, true));
    return x;
}

__global__ __launch_bounds__(256, 4) void band_attn_kernel(
    const float* __restrict__ Q,
    const float* __restrict__ K,
    const float* __restrict__ V,
    const int*   __restrict__ M,
    float* __restrict__ O)
{
    __shared__ __align__(16) float tile[2 * kRowsP * kPad];  // 39168 B

    const int tid  = threadIdx.x;
    const int lane = tid & 63;
    const int wid  = tid >> 6;
    const int blk  = blockIdx.x;
    const int b    = blk >> 8;                 // 256 blocks per batch
    const int t0   = (blk & 255) << 4;         // first query of block
    const int tw   = t0 + 4 * wid;             // first query of this wave
    const int roww = b * kT + tw;

    const int g = lane >> 3;   // subgroup 0..7 (band slot)
    const int r = lane & 7;    // dims 8r..8r+7

    const float* kb = K + (size_t)b * kT * kD;
    const float* vb = V + (size_t)b * kT * kD;
    const int*   mb = M + b * kT;

    // load + pre-scale this wave's four query rows
    float4 q[kQ][2];
    #pragma unroll
    for (int j = 0; j < kQ; ++j) {
        const float* qr = Q + (size_t)(roww + j) * kD + 8 * r;
        q[j][0] = *reinterpret_cast<const float4*>(qr);
        q[j][1] = *reinterpret_cast<const float4*>(qr + 4);
        q[j][0].x *= 0.125f; q[j][0].y *= 0.125f; q[j][0].z *= 0.125f; q[j][0].w *= 0.125f;
        q[j][1].x *= 0.125f; q[j][1].y *= 0.125f; q[j][1].z *= 0.125f; q[j][1].w *= 0.125f;
    }

    // block-uniform: all 16 queries banded?
    bool allq = true;
    #pragma unroll
    for (int jj = 0; jj < kQB; ++jj) allq = allq && (mb[t0 + jj] != 0);

    if (allq) {
        // -------- fast path: LDS-tiled band processing --------
        const int wbase = 4 * wid;   // wave's band origin in union coords

        // slot-validity bits (18 = 2 passes x 9 iters):
        // valid = slot within this wave+pass range, key row exists, mask[s]=1
        unsigned mv = 0u;
        #pragma unroll
        for (int p = 0; p < 2; ++p) {
            const int lo_u = (wbase > kRowsP * p) ? wbase : kRowsP * p;
            const int hi_a = wbase + 2 * kBand + kQ - 1;          // 4w+131
            const int hi_b = kRowsP * p + kRowsP - 1;             // 72p+71
            const int hi_u = (hi_a < hi_b) ? hi_a : hi_b;
            #pragma unroll
            for (int i = 0; i < 9; ++i) {
                const int u = lo_u + g + 8 * i;
                const int s = t0 - kBand + u;
                int sc = s; if (sc < 0) sc = 0; if (sc > kT - 1) sc = kT - 1;
                const bool ok = (u <= hi_u) && (s >= 0) && (s <= kT - 1) && (mb[sc] != 0);
                mv |= (ok ? 1u : 0u) << (p * 9 + i);
            }
        }

        // online-softmax state (statically indexed only)
        float  m_[kQ] = {kInitM, kInitM, kInitM, kInitM};
        float  l_[kQ] = {0.f, 0.f, 0.f, 0.f};
        float4 a_[kQ][2];
        #pragma unroll
        for (int j = 0; j < kQ; ++j) {
            a_[j][0] = make_float4(0.f, 0.f, 0.f, 0.f);
            a_[j][1] = make_float4(0.f, 0.f, 0.f, 0.f);
        }

        #pragma unroll
        for (int p = 0; p < 2; ++p) {
            if (p) __syncthreads();   // wait: pass-0 compute done before overwrite

            // ---- stage 72 rows of K and V into LDS ----
            // 2304 float4 slots, 9 per thread; rows padded to 68 floats.
            #pragma unroll
            for (int i = 0; i < 9; ++i) {
                const int idx  = i * 256 + tid;
                const int arr  = idx >= 1152;            // 0 = K, 1 = V
                const int ridx = idx - (arr ? 1152 : 0);
                const int row  = ridx >> 4;
                const int slot = ridx & 15;
                int s = t0 - kBand + kRowsP * p + row;
                if (s < 0) s = 0; if (s > kT - 1) s = kT - 1;   // clamp (masked later)
                const float* src = (arr ? vb : kb) + (size_t)s * kD + slot * 4;
                const float4 val = *reinterpret_cast<const float4*>(src);
                *reinterpret_cast<float4*>(
                    &tile[(arr ? kVOff : 0) + row * kPad + slot * 4]) = val;
            }
            __syncthreads();

            // ---- compute this pass ----
            const int lo_u = (wbase > kRowsP * p) ? wbase : kRowsP * p;
            #pragma unroll
            for (int i = 0; i < 9; ++i) {
                const int u  = lo_u + g + 8 * i;
                int rl = u - kRowsP * p;
                if (rl > kRowsP - 1) rl = kRowsP - 1;    // clamp (slot masked)
                const bool okslot = (mv >> (p * 9 + i)) & 1u;
                const int  e = u - wbase;                 // s - tw + 64

                const float4 K0 = *reinterpret_cast<const float4*>(&tile[rl * kPad + 8 * r]);
                const float4 K1 = *reinterpret_cast<const float4*>(&tile[rl * kPad + 8 * r + 4]);
                const float4 V0 = *reinterpret_cast<const float4*>(&tile[kVOff + rl * kPad + 8 * r]);
                const float4 V1 = *reinterpret_cast<const float4*>(&tile[kVOff + rl * kPad + 8 * r + 4]);

                float dv[kQ];
                #pragma unroll
                for (int j = 0; j < kQ; ++j) {
                    float d = q[j][0].x * K0.x + q[j][0].y * K0.y
                            + q[j][0].z * K0.z + q[j][0].w * K0.w
                            + q[j][1].x * K1.x + q[j][1].y * K1.y
                            + q[j][1].z * K1.z + q[j][1].w * K1.w;
                    d = sum8_dpp(d);
                    const bool band = (unsigned)(e - j) <= (unsigned)(2 * kBand);
                    dv[j] = (okslot && band) ? d : -1e30f;
                }

                // deferred-max: rescale only if a score exceeds m+thr (rare/never)
                const bool need = (dv[0] > m_[0] + kThr) | (dv[1] > m_[1] + kThr)
                                | (dv[2] > m_[2] + kThr) | (dv[3] > m_[3] + kThr);
                if (__any(need)) {
                    #pragma unroll
                    for (int j = 0; j < kQ; ++j) {
                        const float nm  = fmaxf(m_[j], dv[j]);
                        const float scl = __expf(m_[j] - nm);
                        l_[j] *= scl;
                        a_[j][0].x *= scl; a_[j][0].y *= scl;
                        a_[j][0].z *= scl; a_[j][0].w *= scl;
                        a_[j][1].x *= scl; a_[j][1].y *= scl;
                        a_[j][1].z *= scl; a_[j][1].w *= scl;
                        m_[j] = nm;
                    }
                }

                #pragma unroll
                for (int j = 0; j < kQ; ++j) {
                    const float w = __expf(dv[j] - m_[j]);   // exp(-1e30)=0 masked
                    l_[j] += w;
                    a_[j][0].x += w * V0.x; a_[j][0].y += w * V0.y;
                    a_[j][0].z += w * V0.z; a_[j][0].w += w * V0.w;
                    a_[j][1].x += w * V1.x; a_[j][1].y += w * V1.y;
                    a_[j][1].z += w * V1.z; a_[j][1].w += w * V1.w;
                }
            }
        }

        // ---- merge the 8 subgroup states ----
        #pragma unroll
        for (int j = 0; j < kQ; ++j) {
            float Mx = m_[j];
            Mx = fmaxf(Mx, __shfl_xor(Mx, 8, 64));
            Mx = fmaxf(Mx, __shfl_xor(Mx, 16, 64));
            Mx = fmaxf(Mx, __shfl_xor(Mx, 32, 64));
            const float scl = __expf(m_[j] - Mx);
            l_[j] *= scl;
            a_[j][0].x *= scl; a_[j][0].y *= scl;
            a_[j][0].z *= scl; a_[j][0].w *= scl;
            a_[j][1].x *= scl; a_[j][1].y *= scl;
            a_[j][1].z *= scl; a_[j][1].w *= scl;
        }
        #pragma unroll
        for (int off = 8; off <= 32; off <<= 1) {
            #pragma unroll
            for (int j = 0; j < kQ; ++j) {
                l_[j] += __shfl_xor(l_[j], off, 64);
                a_[j][0].x += __shfl_xor(a_[j][0].x, off, 64);
                a_[j][0].y += __shfl_xor(a_[j][0].y, off, 64);
                a_[j][0].z += __shfl_xor(a_[j][0].z, off, 64);
                a_[j][0].w += __shfl_xor(a_[j][0].w, off, 64);
                a_[j][1].x += __shfl_xor(a_[j][1].x, off, 64);
                a_[j][1].y += __shfl_xor(a_[j][1].y, off, 64);
                a_[j][1].z += __shfl_xor(a_[j][1].z, off, 64);
                a_[j][1].w += __shfl_xor(a_[j][1].w, off, 64);
            }
        }

        // output: subgroup J writes query J (compile-time indices only)
        #define WRITE_OUT(J)                                                  \
            if (g == (J)) {                                                   \
                const float inv = 1.0f / l_[(J)];                             \
                float* orow = O + (size_t)(roww + (J)) * kD + 8 * r;          \
                float4 o0, o1;                                                \
                o0.x = a_[(J)][0].x * inv; o0.y = a_[(J)][0].y * inv;         \
                o0.z = a_[(J)][0].z * inv; o0.w = a_[(J)][0].w * inv;         \
                o1.x = a_[(J)][1].x * inv; o1.y = a_[(J)][1].y * inv;         \
                o1.z = a_[(J)][1].z * inv; o1.w = a_[(J)][1].w * inv;         \
                *reinterpret_cast<float4*>(orow)     = o0;                    \
                *reinterpret_cast<float4*>(orow + 4) = o1;                    \
            }
        WRITE_OUT(0)
        WRITE_OUT(1)
        WRITE_OUT(2)
        WRITE_OUT(3)
        #undef WRITE_OUT
        return;
    }

    // -------- generic fallback (not hit by the bench mask) --------
    // streaming per-wave, fully unrolled so q[qq] stays statically indexed
    #pragma unroll
    for (int qq = 0; qq < kQ; ++qq) {
        const int t  = tw + qq;
        const int qm = mb[t];
        const float4 q0 = q[qq][0];
        const float4 q1 = q[qq][1];
        int lo, hi;
        if (qm) {
            lo = t - kBand; if (lo < 0) lo = 0;
            hi = t + kBand; if (hi > kT - 1) hi = kT - 1;
        } else {
            lo = 0; hi = kT - 1;
        }
        float m = -INFINITY, l = 0.f;
        float4 acc0 = make_float4(0.f,0.f,0.f,0.f), acc1 = acc0;
        for (int s = lo + g; s <= hi; s += 8) {
            const float* kr = kb + (size_t)s * kD + 8 * r;
            const float4 k0 = *reinterpret_cast<const float4*>(kr);
            const float4 k1 = *reinterpret_cast<const float4*>(kr + 4);
            float d = q0.x * k0.x + q0.y * k0.y + q0.z * k0.z + q0.w * k0.w
                    + q1.x * k1.x + q1.y * k1.y + q1.z * k1.z + q1.w * k1.w;
            d = sum8_dpp(d);
            if (mb[s]) {
                if (d > m) {
                    const float scl = __expf(m - d);
                    l *= scl;
                    acc0.x *= scl; acc0.y *= scl; acc0.z *= scl; acc0.w *= scl;
                    acc1.x *= scl; acc1.y *= scl; acc1.z *= scl; acc1.w *= scl;
                    m = d;
                }
                const float w = __expf(d - m);
                const float* vr = vb + (size_t)s * kD + 8 * r;
                const float4 v0 = *reinterpret_cast<const float4*>(vr);
                const float4 v1 = *reinterpret_cast<const float4*>(vr + 4);
                l += w;
                acc0.x += w * v0.x; acc0.y += w * v0.y;
                acc0.z += w * v0.z; acc0.w += w * v0.w;
                acc1.x += w * v1.x; acc1.y += w * v1.y;
                acc1.z += w * v1.z; acc1.w += w * v1.w;
            }
        }
        float Mx = m;
        Mx = fmaxf(Mx, __shfl_xor(Mx, 8, 64));
        Mx = fmaxf(Mx, __shfl_xor(Mx, 16, 64));
        Mx = fmaxf(Mx, __shfl_xor(Mx, 32, 64));
        const float scl = __expf(m - Mx);
        l *= scl;
        acc0.x *= scl; acc0.y *= scl; acc0.z *= scl; acc0.w *= scl;
        acc1.x *= scl; acc1.y *= scl; acc1.z *= scl; acc1.w *= scl;
        #pragma unroll
        for (int off = 8; off <= 32; off <<= 1) {
            l += __shfl_xor(l, off, 64);
            acc0.x += __shfl_xor(acc0.x, off, 64);
            acc0.y += __shfl_xor(acc0.y, off, 64);
            acc0.z += __shfl_xor(acc0.z, off, 64);
            acc0.w += __shfl_xor(acc0.w, off, 64);
            acc1.x += __shfl_xor(acc1.x, off, 64);
            acc1.y += __shfl_xor(acc1.y, off, 64);
            acc1.z += __shfl_xor(acc1.z, off, 64);
            acc1.w += __shfl_xor(acc1.w, off, 64);
        }
        if (g == 0) {
            const float inv = 1.0f / l;
            float* orow = O + (size_t)(b * kT + t) * kD + 8 * r;
            float4 o0, o1;
            o0.x = acc0.x * inv; o0.y = acc0.y * inv;
            o0.z = acc0.z * inv; o0.w = acc0.w * inv;
            o1.x = acc1.x * inv; o1.y = acc1.y * inv;
            o1.z = acc1.z * inv; o1.w = acc1.w * inv;
            *reinterpret_cast<float4*>(orow)     = o0;
            *reinterpret_cast<float4*>(orow + 4) = o1;
        }
    }
}

extern "C" void kernel_launch(void* const* d_in, const int* in_sizes, int n_in,
                              void* d_out, int out_size, void* d_ws, size_t ws_size,
                              hipStream_t stream) {
    const float* q    = (const float*)d_in[0];
    const float* k    = (const float*)d_in[1];
    const float* v    = (const float*)d_in[2];
    const int*   mask = (const int*)d_in[3];
    float*       out  = (float*)d_out;

    const int blocks = (kB * kT) / kQB;       // 1024 blocks, 16 queries each
    dim3 grid(blocks);
    dim3 block(256);
    band_attn_kernel<<<grid, block, 0, stream>>>(q, k, v, mask, out);
}

// Round 8
// 29.879 us; speedup vs baseline: 2.4520x; 2.4152x over previous
//
#include <hip/hip_runtime.h>
#include <math.h>

// Banded self-attention, fp32. B=4, T=4096, D=64, MASK_NUM=64.
// One 64-lane wave handles FOUR consecutive query rows; each K/V row load
// feeds four dots. 8 subgroups of 8 lanes; subgroup g handles key slots
// s = s_lo+g+8i (17 slots cover the 131+3-row union band). Lane r of a
// subgroup owns dims [8r, 8r+8).
// Fused single pass, deferred-max online softmax (T13): m starts at 0 and
// is raised only when a score exceeds m+8 (wave-uniform __any; ~never on
// N(0,1) data). Exact: merge applies the true max.
// Depth-1 double-buffer prefetch; buffer indices are COMPILE-TIME constants
// via STEP(I) macros (R4/R6/R7 lesson: any runtime indexing or tight
// launch-bounds occupancy hint -> allocator spills -> 2x regression).
// Config locked to the only proven no-spill envelope: 256-thread blocks,
// __launch_bounds__(256,2)  (R3: 112 VGPR, zero scratch).
// XCD-chunked block swizzle: adjacent blocks share 128/144 band rows; give
// each XCD a contiguous logical range so re-reads hit its own L2.

constexpr int   kB     = 4;
constexpr int   kT     = 4096;
constexpr int   kD     = 64;
constexpr int   kBand  = 64;   // MASK_NUM
constexpr int   kQ     = 4;    // queries per wave
constexpr int   kIters = 17;   // ceil((2*kBand + kQ)/8)
constexpr float kThr   = 8.0f; // deferred-max threshold
constexpr float kInitM = 0.0f;

__device__ __forceinline__ float sum8_dpp(float x) {
    // all-lanes sum within each 8-lane group:
    // quad_perm xor1 (0xB1), quad_perm xor2 (0x4E), row_half_mirror (0x141)
    int v = __float_as_int(x);
    x += __int_as_float(__builtin_amdgcn_update_dpp(0, v, 0xB1, 0xF, 0xF, true));
    v = __float_as_int(x);
    x += __int_as_float(__builtin_amdgcn_update_dpp(0, v, 0x4E, 0xF, 0xF, true));
    v = __float_as_int(x);
    x += __int_as_float(__builtin_amdgcn_update_dpp(0, v, 0x141, 0xF, 0xF, true));
    return x;
}

__global__ __launch_bounds__(256, 2) void band_attn_kernel(
    const float* __restrict__ Q,
    const float* __restrict__ K,
    const float* __restrict__ V,
    const int*   __restrict__ M,
    float* __restrict__ O)
{
    const int lane = threadIdx.x & 63;
    const int wid  = threadIdx.x >> 6;

    // XCD-chunked swizzle (1024 blocks, 8 XCDs, 128 per XCD; bijective)
    const int phys = blockIdx.x;
    const int blk  = (phys & 7) * 128 + (phys >> 3);

    const int b  = blk >> 8;                  // 256 blocks per batch
    const int t0 = (blk & 255) << 4;          // block's first query
    const int tw = t0 + 4 * wid;              // this wave's first query
    const int roww = b * kT + tw;

    const int g = lane >> 3;   // subgroup 0..7 (key slot)
    const int r = lane & 7;    // dims 8r..8r+7

    // load + pre-scale the four query rows (each lane: dims 8r..8r+7)
    float4 q[kQ][2];
    #pragma unroll
    for (int j = 0; j < kQ; ++j) {
        const float* qr = Q + (size_t)(roww + j) * kD + 8 * r;
        q[j][0] = *reinterpret_cast<const float4*>(qr);
        q[j][1] = *reinterpret_cast<const float4*>(qr + 4);
        q[j][0].x *= 0.125f; q[j][0].y *= 0.125f; q[j][0].z *= 0.125f; q[j][0].w *= 0.125f;
        q[j][1].x *= 0.125f; q[j][1].y *= 0.125f; q[j][1].z *= 0.125f; q[j][1].w *= 0.125f;
    }

    const float* kb = K + (size_t)b * kT * kD;
    const float* vb = V + (size_t)b * kT * kD;
    const int*   mb = M + b * kT;

    const bool allq = mb[tw] && mb[tw + 1] && mb[tw + 2] && mb[tw + 3];

    if (allq) {
        // -------- fast path: all four queries banded --------
        int s_lo = tw - kBand;            if (s_lo < 0) s_lo = 0;
        int s_hi = tw + (kQ - 1) + kBand; if (s_hi > kT - 1) s_hi = kT - 1;
        const int s0 = s_lo + g;
        const int e0 = s0 - tw + kBand;   // band coordinate of slot i=0

        // key-mask bits, one per slot
        unsigned mv = 0u;
        #pragma unroll
        for (int i = 0; i < kIters; ++i) {
            const int s  = s0 + 8 * i;
            const int sc = (s <= s_hi) ? s : s_hi;
            mv |= (mb[sc] ? 1u : 0u) << i;
        }

        // online-softmax state (statically indexed only)
        float  m_[kQ] = {kInitM, kInitM, kInitM, kInitM};
        float  l_[kQ] = {0.f, 0.f, 0.f, 0.f};
        float4 a_[kQ][2];
        #pragma unroll
        for (int j = 0; j < kQ; ++j) {
            a_[j][0] = make_float4(0.f, 0.f, 0.f, 0.f);
            a_[j][1] = make_float4(0.f, 0.f, 0.f, 0.f);
        }

        // two K/V register buffer sets; ALL indices compile-time constants
        float4 ka[2], kc[2], va[2], vc[2];

        #define LOADKV(S, I) do {                                             \
            const int s_  = s0 + 8 * (I);                                     \
            const int sc_ = (s_ <= s_hi) ? s_ : s_hi;                         \
            const float* kr_ = kb + (size_t)sc_ * kD + 8 * r;                 \
            const float* vr_ = vb + (size_t)sc_ * kD + 8 * r;                 \
            ka[(S)] = *reinterpret_cast<const float4*>(kr_);                  \
            kc[(S)] = *reinterpret_cast<const float4*>(kr_ + 4);              \
            va[(S)] = *reinterpret_cast<const float4*>(vr_);                  \
            vc[(S)] = *reinterpret_cast<const float4*>(vr_ + 4);              \
        } while (0)

        #define COMPUTE(S, I) do {                                            \
            const int  s_  = s0 + 8 * (I);                                    \
            const bool ok_ = (s_ <= s_hi) && ((mv >> (I)) & 1u);              \
            const int  e_  = e0 + 8 * (I);                                    \
            float dv[kQ];                                                     \
            _Pragma("unroll")                                                 \
            for (int j = 0; j < kQ; ++j) {                                    \
                float d = q[j][0].x * ka[(S)].x + q[j][0].y * ka[(S)].y       \
                        + q[j][0].z * ka[(S)].z + q[j][0].w * ka[(S)].w       \
                        + q[j][1].x * kc[(S)].x + q[j][1].y * kc[(S)].y       \
                        + q[j][1].z * kc[(S)].z + q[j][1].w * kc[(S)].w;      \
                d = sum8_dpp(d);                                              \
                const bool band_ = (unsigned)(e_ - j) <= (unsigned)(2 * kBand);\
                dv[j] = (ok_ && band_) ? d : -1e30f;                          \
            }                                                                 \
            const bool need_ = (dv[0] > m_[0] + kThr) | (dv[1] > m_[1] + kThr)\
                             | (dv[2] > m_[2] + kThr) | (dv[3] > m_[3] + kThr);\
            if (__any(need_)) {                                               \
                _Pragma("unroll")                                             \
                for (int j = 0; j < kQ; ++j) {                                \
                    const float nm  = fmaxf(m_[j], dv[j]);                    \
                    const float scl = __expf(m_[j] - nm);                     \
                    l_[j] *= scl;                                             \
                    a_[j][0].x *= scl; a_[j][0].y *= scl;                     \
                    a_[j][0].z *= scl; a_[j][0].w *= scl;                     \
                    a_[j][1].x *= scl; a_[j][1].y *= scl;                     \
                    a_[j][1].z *= scl; a_[j][1].w *= scl;                     \
                    m_[j] = nm;                                               \
                }                                                             \
            }                                                                 \
            _Pragma("unroll")                                                 \
            for (int j = 0; j < kQ; ++j) {                                    \
                const float w = __expf(dv[j] - m_[j]);                        \
                l_[j] += w;                                                   \
                a_[j][0].x += w * va[(S)].x; a_[j][0].y += w * va[(S)].y;     \
                a_[j][0].z += w * va[(S)].z; a_[j][0].w += w * va[(S)].w;     \
                a_[j][1].x += w * vc[(S)].x; a_[j][1].y += w * vc[(S)].y;     \
                a_[j][1].z += w * vc[(S)].z; a_[j][1].w += w * vc[(S)].w;     \
            }                                                                 \
        } while (0)

        // depth-1 software pipeline, fully unrolled, static buffer indices
        #define STEP(I)                                                       \
            { if ((I) + 1 < kIters) LOADKV(((I) + 1) & 1, (I) + 1);           \
              COMPUTE((I) & 1, (I)); }

        LOADKV(0, 0);
        STEP(0)  STEP(1)  STEP(2)  STEP(3)  STEP(4)  STEP(5)
        STEP(6)  STEP(7)  STEP(8)  STEP(9)  STEP(10) STEP(11)
        STEP(12) STEP(13) STEP(14) STEP(15) STEP(16)

        #undef STEP
        #undef COMPUTE
        #undef LOADKV

        // ---- merge the 8 subgroup states ----
        #pragma unroll
        for (int j = 0; j < kQ; ++j) {
            float Mx = m_[j];
            Mx = fmaxf(Mx, __shfl_xor(Mx, 8, 64));
            Mx = fmaxf(Mx, __shfl_xor(Mx, 16, 64));
            Mx = fmaxf(Mx, __shfl_xor(Mx, 32, 64));
            const float scl = __expf(m_[j] - Mx);
            l_[j] *= scl;
            a_[j][0].x *= scl; a_[j][0].y *= scl;
            a_[j][0].z *= scl; a_[j][0].w *= scl;
            a_[j][1].x *= scl; a_[j][1].y *= scl;
            a_[j][1].z *= scl; a_[j][1].w *= scl;
        }
        #pragma unroll
        for (int off = 8; off <= 32; off <<= 1) {
            #pragma unroll
            for (int j = 0; j < kQ; ++j) {
                l_[j] += __shfl_xor(l_[j], off, 64);
                a_[j][0].x += __shfl_xor(a_[j][0].x, off, 64);
                a_[j][0].y += __shfl_xor(a_[j][0].y, off, 64);
                a_[j][0].z += __shfl_xor(a_[j][0].z, off, 64);
                a_[j][0].w += __shfl_xor(a_[j][0].w, off, 64);
                a_[j][1].x += __shfl_xor(a_[j][1].x, off, 64);
                a_[j][1].y += __shfl_xor(a_[j][1].y, off, 64);
                a_[j][1].z += __shfl_xor(a_[j][1].z, off, 64);
                a_[j][1].w += __shfl_xor(a_[j][1].w, off, 64);
            }
        }

        // output: subgroup J writes query J (compile-time indices only)
        #define WRITE_OUT(J)                                                  \
            if (g == (J)) {                                                   \
                const float inv = 1.0f / l_[(J)];                             \
                float* orow = O + (size_t)(roww + (J)) * kD + 8 * r;          \
                float4 o0, o1;                                                \
                o0.x = a_[(J)][0].x * inv; o0.y = a_[(J)][0].y * inv;         \
                o0.z = a_[(J)][0].z * inv; o0.w = a_[(J)][0].w * inv;         \
                o1.x = a_[(J)][1].x * inv; o1.y = a_[(J)][1].y * inv;         \
                o1.z = a_[(J)][1].z * inv; o1.w = a_[(J)][1].w * inv;         \
                *reinterpret_cast<float4*>(orow)     = o0;                    \
                *reinterpret_cast<float4*>(orow + 4) = o1;                    \
            }
        WRITE_OUT(0)
        WRITE_OUT(1)
        WRITE_OUT(2)
        WRITE_OUT(3)
        #undef WRITE_OUT
        return;
    }

    // -------- generic fallback (not hit by the bench mask) --------
    // fully unrolled so q[qq] stays statically indexed (no scratch)
    #pragma unroll
    for (int qq = 0; qq < kQ; ++qq) {
        const int t  = tw + qq;
        const int qm = mb[t];
        const float4 q0 = q[qq][0];
        const float4 q1 = q[qq][1];
        int lo, hi;
        if (qm) {
            lo = t - kBand; if (lo < 0) lo = 0;
            hi = t + kBand; if (hi > kT - 1) hi = kT - 1;
        } else {
            lo = 0; hi = kT - 1;
        }
        float m = -INFINITY, l = 0.f;
        float4 acc0 = make_float4(0.f,0.f,0.f,0.f), acc1 = acc0;
        for (int s = lo + g; s <= hi; s += 8) {
            const float* kr = kb + (size_t)s * kD + 8 * r;
            const float4 k0 = *reinterpret_cast<const float4*>(kr);
            const float4 k1 = *reinterpret_cast<const float4*>(kr + 4);
            float d = q0.x * k0.x + q0.y * k0.y + q0.z * k0.z + q0.w * k0.w
                    + q1.x * k1.x + q1.y * k1.y + q1.z * k1.z + q1.w * k1.w;
            d = sum8_dpp(d);
            if (mb[s]) {
                if (d > m) {
                    const float scl = __expf(m - d);
                    l *= scl;
                    acc0.x *= scl; acc0.y *= scl; acc0.z *= scl; acc0.w *= scl;
                    acc1.x *= scl; acc1.y *= scl; acc1.z *= scl; acc1.w *= scl;
                    m = d;
                }
                const float w = __expf(d - m);
                const float* vr = vb + (size_t)s * kD + 8 * r;
                const float4 v0 = *reinterpret_cast<const float4*>(vr);
                const float4 v1 = *reinterpret_cast<const float4*>(vr + 4);
                l += w;
                acc0.x += w * v0.x; acc0.y += w * v0.y;
                acc0.z += w * v0.z; acc0.w += w * v0.w;
                acc1.x += w * v1.x; acc1.y += w * v1.y;
                acc1.z += w * v1.z; acc1.w += w * v1.w;
            }
        }
        float Mx = m;
        Mx = fmaxf(Mx, __shfl_xor(Mx, 8, 64));
        Mx = fmaxf(Mx, __shfl_xor(Mx, 16, 64));
        Mx = fmaxf(Mx, __shfl_xor(Mx, 32, 64));
        const float scl = __expf(m - Mx);
        l *= scl;
        acc0.x *= scl; acc0.y *= scl; acc0.z *= scl; acc0.w *= scl;
        acc1.x *= scl; acc1.y *= scl; acc1.z *= scl; acc1.w *= scl;
        #pragma unroll
        for (int off = 8; off <= 32; off <<= 1) {
            l += __shfl_xor(l, off, 64);
            acc0.x += __shfl_xor(acc0.x, off, 64);
            acc0.y += __shfl_xor(acc0.y, off, 64);
            acc0.z += __shfl_xor(acc0.z, off, 64);
            acc0.w += __shfl_xor(acc0.w, off, 64);
            acc1.x += __shfl_xor(acc1.x, off, 64);
            acc1.y += __shfl_xor(acc1.y, off, 64);
            acc1.z += __shfl_xor(acc1.z, off, 64);
            acc1.w += __shfl_xor(acc1.w, off, 64);
        }
        if (g == 0) {
            const float inv = 1.0f / l;
            float* orow = O + (size_t)(b * kT + t) * kD + 8 * r;
            float4 o0, o1;
            o0.x = acc0.x * inv; o0.y = acc0.y * inv;
            o0.z = acc0.z * inv; o0.w = acc0.w * inv;
            o1.x = acc1.x * inv; o1.y = acc1.y * inv;
            o1.z = acc1.z * inv; o1.w = acc1.w * inv;
            *reinterpret_cast<float4*>(orow)     = o0;
            *reinterpret_cast<float4*>(orow + 4) = o1;
        }
    }
}

extern "C" void kernel_launch(void* const* d_in, const int* in_sizes, int n_in,
                              void* d_out, int out_size, void* d_ws, size_t ws_size,
                              hipStream_t stream) {
    const float* q    = (const float*)d_in[0];
    const float* k    = (const float*)d_in[1];
    const float* v    = (const float*)d_in[2];
    const int*   mask = (const int*)d_in[3];
    float*       out  = (float*)d_out;

    const int blocks = (kB * kT) / (4 * kQ);  // 1024 blocks (4 waves x 4 queries)
    dim3 grid(blocks);
    dim3 block(256);
    band_attn_kernel<<<grid, block, 0, stream>>>(q, k, v, mask, out);
}

// Round 10
// 12.968 us; speedup vs baseline: 5.6493x; 2.3040x over previous
//
#include <hip/hip_runtime.h>
#include <math.h>

// Banded self-attention via MFMA (bf16 inputs, fp32 accumulate).
// B=4, T=4096, D=64, MASK_NUM=64.
// Grid: 256 blocks x 256 threads (1 block/CU). Block = 64 queries [tB,tB+64);
// union band = 192 keys [tB-64, tB+128) staged in LDS once:
//   Ks[192][72] bf16 row-major, d-chunk XOR swizzle (d' = d ^ ((u&3)<<3))
//   Vs[64][264] bf16 TRANSPOSED (V^T), k XOR-rotation swizzle (k' = k ^ (s(d)<<3))
// Wave w handles 16 queries [tw, tw+16), key window = block rows [16w, 16w+144)
// (PV pads to 160 with zero-weight keys; the V^T tail [192,264) of each LDS
// row is ZEROED — R9 lesson: stale LDS there was Inf/NaN and 0 x Inf = NaN).
// QK^T: S^T = K·Q^T via mfma_f32_16x16x32_bf16 (A=K-tile from LDS, B=Q^T).
// D layout (HW-verified): col = lane&15 = query, row = 4*(lane>>4)+reg = key
// -> softmax is lane-local over 36 regs + shfl_xor(16,32).
// PV: O^T = V^T·P^T (A=V^T b128 reads, B=P^T built by shfl redistribution).
// A/B share the per-lane k-mapping, so the k-permutation cancels; only the
// verified C/D layout is load-bearing.
// Generic mask semantics preserved via block-uniform fallback.

typedef __attribute__((ext_vector_type(8))) short bf16x8;
typedef __attribute__((ext_vector_type(4))) float f32x4;

constexpr int kT    = 4096;
constexpr int kD    = 64;
constexpr int kBand = 64;   // MASK_NUM
constexpr int KP    = 72;   // K LDS pitch (bf16 elems), 144 B rows (16B-aligned)
constexpr int VP    = 264;  // V^T LDS pitch (bf16 elems), 528 B rows (16B-aligned)

__device__ __forceinline__ short f2bf(float x) {
    // fast round-to-nearest-ish f32 -> bf16 (inputs are tame: N(0,1)-scale)
    return (short)((__float_as_uint(x) + 0x8000u) >> 16);
}

__global__ __launch_bounds__(256, 1) void mfma_band_attn(
    const float* __restrict__ Q,
    const float* __restrict__ K,
    const float* __restrict__ V,
    const int*   __restrict__ M,
    float* __restrict__ O)
{
    __shared__ short Ks[192 * KP];
    __shared__ short Vs[64 * VP];
    __shared__ int   wflag[4];

    const int tid  = threadIdx.x;
    const int lane = tid & 63;
    const int wid  = tid >> 6;
    const int blk  = blockIdx.x;          // 256 blocks
    const int b    = blk >> 6;            // 64 query-blocks per batch
    const int tB   = (blk & 63) << 6;     // block's first query
    const int tw   = tB + 16 * wid;       // wave's first query
    const int h    = lane >> 4;           // 0..3
    const int q    = lane & 15;           // query col (B/D role) / key row (A role)

    const float* Qg = Q + (size_t)b * kT * kD;
    const float* Kg = K + (size_t)b * kT * kD;
    const float* Vg = V + (size_t)b * kT * kD;
    const int*   mb = M + b * kT;

    // ---- Q fragments (B-operand of QK): lane (h,q) holds Q[tw+q][..]*0.125 ----
    bf16x8 qf0, qf1;
    {
        const float* qp = Qg + (size_t)(tw + q) * kD + 8 * h;
        float4 a0 = *(const float4*)(qp + 0);
        float4 a1 = *(const float4*)(qp + 4);
        float4 b0 = *(const float4*)(qp + 32);
        float4 b1 = *(const float4*)(qp + 36);
        qf0[0] = f2bf(a0.x * 0.125f); qf0[1] = f2bf(a0.y * 0.125f);
        qf0[2] = f2bf(a0.z * 0.125f); qf0[3] = f2bf(a0.w * 0.125f);
        qf0[4] = f2bf(a1.x * 0.125f); qf0[5] = f2bf(a1.y * 0.125f);
        qf0[6] = f2bf(a1.z * 0.125f); qf0[7] = f2bf(a1.w * 0.125f);
        qf1[0] = f2bf(b0.x * 0.125f); qf1[1] = f2bf(b0.y * 0.125f);
        qf1[2] = f2bf(b0.z * 0.125f); qf1[3] = f2bf(b0.w * 0.125f);
        qf1[4] = f2bf(b1.x * 0.125f); qf1[5] = f2bf(b1.y * 0.125f);
        qf1[6] = f2bf(b1.z * 0.125f); qf1[7] = f2bf(b1.w * 0.125f);
    }

    // ---- mask check for the fast path (window keys + the 64 queries) ----
    int ok = 1;
    if (tid < 192) {
        int ka = tB - 64 + tid;
        if ((unsigned)ka < (unsigned)kT && !mb[ka]) ok = 0;
    }
    if (tid < 64) { if (!mb[tB + tid]) ok = 0; }
    ok = __all(ok);
    if (lane == 0) wflag[wid] = ok;

    // ---- stage K (row-major bf16, swizzled): 192 rows x 16 float4-slots ----
    #pragma unroll
    for (int i = 0; i < 12; ++i) {
        const int idx = i * 256 + tid;          // 0..3071
        const int u   = idx >> 4;
        const int dc  = (idx & 15) << 2;        // 4-float group base
        int ka = tB - 64 + u;
        ka = ka < 0 ? 0 : (ka > kT - 1 ? kT - 1 : ka);
        const float4 f = *(const float4*)(Kg + (size_t)ka * kD + dc);
        const unsigned lo = ((unsigned)(unsigned short)f2bf(f.y) << 16) | (unsigned short)f2bf(f.x);
        const unsigned hi = ((unsigned)(unsigned short)f2bf(f.w) << 16) | (unsigned short)f2bf(f.z);
        *(uint2*)&Ks[u * KP + (dc ^ ((u & 3) << 3))] = make_uint2(lo, hi);
    }
    // ---- stage V transposed (V^T[d][k], swizzled): wave w -> keys 48w..48w+47 ----
    {
        const int d  = lane;
        const int sw = (d + (d >> 3)) & 7;
        short* vrow = &Vs[d * VP];
        #pragma unroll 8
        for (int jr = 0; jr < 48; ++jr) {
            const int u = 48 * wid + jr;
            int ka = tB - 64 + u;
            ka = ka < 0 ? 0 : (ka > kT - 1 ? kT - 1 : ka);
            vrow[u ^ (sw << 3)] = f2bf(Vg[(size_t)ka * kD + d]);
        }
    }
    // ---- zero the V^T tail [192, 264) of every row (R9 NaN fix) ----
    // PV's padded k-step reads positions up to 255 for wid=3; their P-weight
    // is 0, but 0 x stale-Inf/NaN = NaN. Disjoint from staged [0,192) (the
    // XOR swizzle is closed within each 64-aligned chunk), so no race.
    #pragma unroll
    for (int i = 0; i < 9; ++i) {
        const int idx = i * 256 + tid;          // 0..2303
        const int row = idx / 36;
        const int col = idx - row * 36;         // 36 uints = 72 shorts
        *(unsigned int*)&Vs[row * VP + 192 + 2 * col] = 0u;
    }
    __syncthreads();

    if (wflag[0] && wflag[1] && wflag[2] && wflag[3]) {
        // ================= fast path (MFMA) =================
        // acc[t][r] = score(key kk = 16t+4h+r (wave-local), query q); acc[9] = 0 pad
        f32x4 acc[10];
        #pragma unroll
        for (int t = 0; t < 10; ++t) acc[t] = (f32x4){0.f, 0.f, 0.f, 0.f};

        // QK^T: A = K-tile (m=key=lane&15, k=d), B = Q^T (n=q, k=d)
        #pragma unroll
        for (int t = 0; t < 9; ++t) {
            const int u  = 16 * wid + 16 * t + q;       // LDS K row (lane&15 = key)
            const short* kr = &Ks[u * KP];
            const int x  = (u & 3) << 3;
            const bf16x8 ka0 = *(const bf16x8*)(kr + ((8 * h) ^ x));
            const bf16x8 ka1 = *(const bf16x8*)(kr + ((32 + 8 * h) ^ x));
            acc[t] = __builtin_amdgcn_mfma_f32_16x16x32_bf16(ka0, qf0, acc[t], 0, 0, 0);
            acc[t] = __builtin_amdgcn_mfma_f32_16x16x32_bf16(ka1, qf1, acc[t], 0, 0, 0);
        }

        // ---- mask + softmax (lane-local over 36 scores, then shfl 16/32) ----
        const int base = tB - 64 + 16 * wid;  // absolute key of wave-local kk=0
        float mx = -1e30f;
        #pragma unroll
        for (int t = 0; t < 9; ++t) {
            #pragma unroll
            for (int r = 0; r < 4; ++r) {
                const int kk = 16 * t + 4 * h + r;
                const int ka = base + kk;
                const bool val = ((unsigned)(kk - q) <= 2u * kBand) &&
                                 ((unsigned)ka < (unsigned)kT);
                const float sc = val ? acc[t][r] : -1e30f;
                acc[t][r] = sc;
                mx = fmaxf(mx, sc);
            }
        }
        mx = fmaxf(mx, __shfl_xor(mx, 16, 64));
        mx = fmaxf(mx, __shfl_xor(mx, 32, 64));
        float lsum = 0.f;
        #pragma unroll
        for (int t = 0; t < 9; ++t) {
            #pragma unroll
            for (int r = 0; r < 4; ++r) {
                const float w = __expf(acc[t][r] - mx);   // exp(-1e30)=0 masked
                acc[t][r] = w;
                lsum += w;
            }
        }
        lsum += __shfl_xor(lsum, 16, 64);
        lsum += __shfl_xor(lsum, 32, 64);

        // ---- PV: O^T = V^T · P^T ----
        f32x4 oacc[4];
        #pragma unroll
        for (int dt = 0; dt < 4; ++dt) oacc[dt] = (f32x4){0.f, 0.f, 0.f, 0.f};

        #pragma unroll
        for (int ks = 0; ks < 5; ++ks) {
            // B-frag (P^T): lane (h,q) element j = P[key 32ks+8h+j][q]
            bf16x8 pf;
            #pragma unroll
            for (int j = 0; j < 8; ++j) {
                const int srcl = 16 * (2 * (h & 1) + (j >> 2)) + q;
                const float vlo = __shfl(acc[2 * ks][j & 3], srcl, 64);
                const float vhi = __shfl(acc[2 * ks + 1][j & 3], srcl, 64);
                pf[j] = f2bf((h < 2) ? vlo : vhi);
            }
            // A-frags (V^T): lane (h, d=16dt+q): keys u0..u0+7 of that d-row
            #pragma unroll
            for (int dt = 0; dt < 4; ++dt) {
                const int d  = 16 * dt + q;
                const int sw = (d + (d >> 3)) & 7;
                const int u0 = (16 * wid + 32 * ks + 8 * h) ^ (sw << 3);
                const bf16x8 vf = *(const bf16x8*)&Vs[d * VP + u0];
                oacc[dt] = __builtin_amdgcn_mfma_f32_16x16x32_bf16(vf, pf, oacc[dt], 0, 0, 0);
            }
        }

        // ---- write O: lane (h,q) holds O[tw+q][16dt+4h+reg] ----
        const float inv = 1.0f / lsum;
        float* Ob = O + (size_t)(b * kT + tw + q) * kD;
        #pragma unroll
        for (int dt = 0; dt < 4; ++dt) {
            float4 o;
            o.x = oacc[dt][0] * inv; o.y = oacc[dt][1] * inv;
            o.z = oacc[dt][2] * inv; o.w = oacc[dt][3] * inv;
            *(float4*)(Ob + 16 * dt + 4 * h) = o;
        }
        return;
    }

    // ================= generic fallback (mask not all-ones; cold) =================
    const int g8 = lane >> 3;
    const int r8 = lane & 7;
    for (int qq = 0; qq < 16; ++qq) {
        const int t  = tw + qq;
        const int qm = mb[t];
        const float* qp = Qg + (size_t)t * kD + 8 * r8;
        float4 q0 = *(const float4*)qp;
        float4 q1 = *(const float4*)(qp + 4);
        q0.x *= 0.125f; q0.y *= 0.125f; q0.z *= 0.125f; q0.w *= 0.125f;
        q1.x *= 0.125f; q1.y *= 0.125f; q1.z *= 0.125f; q1.w *= 0.125f;
        int lo, hi;
        if (qm) {
            lo = t - kBand; if (lo < 0) lo = 0;
            hi = t + kBand; if (hi > kT - 1) hi = kT - 1;
        } else {
            lo = 0; hi = kT - 1;
        }
        float m = -1e30f, l = 0.f;
        float4 a0 = make_float4(0.f, 0.f, 0.f, 0.f), a1 = a0;
        for (int s = lo + g8; s <= hi; s += 8) {
            const float* kr = Kg + (size_t)s * kD + 8 * r8;
            const float4 k0 = *(const float4*)kr;
            const float4 k1 = *(const float4*)(kr + 4);
            float d = q0.x * k0.x + q0.y * k0.y + q0.z * k0.z + q0.w * k0.w
                    + q1.x * k1.x + q1.y * k1.y + q1.z * k1.z + q1.w * k1.w;
            d += __shfl_xor(d, 1, 64);
            d += __shfl_xor(d, 2, 64);
            d += __shfl_xor(d, 4, 64);
            if (mb[s]) {
                if (d > m) {
                    const float scl = __expf(m - d);
                    l *= scl;
                    a0.x *= scl; a0.y *= scl; a0.z *= scl; a0.w *= scl;
                    a1.x *= scl; a1.y *= scl; a1.z *= scl; a1.w *= scl;
                    m = d;
                }
                const float w = __expf(d - m);
                const float* vr = Vg + (size_t)s * kD + 8 * r8;
                const float4 v0 = *(const float4*)vr;
                const float4 v1 = *(const float4*)(vr + 4);
                l += w;
                a0.x += w * v0.x; a0.y += w * v0.y; a0.z += w * v0.z; a0.w += w * v0.w;
                a1.x += w * v1.x; a1.y += w * v1.y; a1.z += w * v1.z; a1.w += w * v1.w;
            }
        }
        float Mx = m;
        Mx = fmaxf(Mx, __shfl_xor(Mx, 8, 64));
        Mx = fmaxf(Mx, __shfl_xor(Mx, 16, 64));
        Mx = fmaxf(Mx, __shfl_xor(Mx, 32, 64));
        const float scl = __expf(m - Mx);
        l *= scl;
        a0.x *= scl; a0.y *= scl; a0.z *= scl; a0.w *= scl;
        a1.x *= scl; a1.y *= scl; a1.z *= scl; a1.w *= scl;
        #pragma unroll
        for (int off = 8; off <= 32; off <<= 1) {
            l += __shfl_xor(l, off, 64);
            a0.x += __shfl_xor(a0.x, off, 64); a0.y += __shfl_xor(a0.y, off, 64);
            a0.z += __shfl_xor(a0.z, off, 64); a0.w += __shfl_xor(a0.w, off, 64);
            a1.x += __shfl_xor(a1.x, off, 64); a1.y += __shfl_xor(a1.y, off, 64);
            a1.z += __shfl_xor(a1.z, off, 64); a1.w += __shfl_xor(a1.w, off, 64);
        }
        if (g8 == 0) {
            const float inv = 1.0f / l;
            float* orow = O + (size_t)(b * kT + t) * kD + 8 * r8;
            float4 o0, o1;
            o0.x = a0.x * inv; o0.y = a0.y * inv; o0.z = a0.z * inv; o0.w = a0.w * inv;
            o1.x = a1.x * inv; o1.y = a1.y * inv; o1.z = a1.z * inv; o1.w = a1.w * inv;
            *(float4*)orow       = o0;
            *(float4*)(orow + 4) = o1;
        }
    }
}

extern "C" void kernel_launch(void* const* d_in, const int* in_sizes, int n_in,
                              void* d_out, int out_size, void* d_ws, size_t ws_size,
                              hipStream_t stream) {
    const float* q    = (const float*)d_in[0];
    const float* k    = (const float*)d_in[1];
    const float* v    = (const float*)d_in[2];
    const int*   mask = (const int*)d_in[3];
    float*       out  = (float*)d_out;
    (void)d_ws; (void)ws_size; (void)in_sizes; (void)n_in; (void)out_size;

    dim3 grid(256);    // 4 batches x 64 query-blocks, 64 queries each
    dim3 block(256);
    mfma_band_attn<<<grid, block, 0, stream>>>(q, k, v, mask, out);
}

// Round 11
// 12.020 us; speedup vs baseline: 6.0951x; 1.0789x over previous
//
#include <hip/hip_runtime.h>
#include <math.h>

// Banded self-attention via MFMA (bf16 inputs, fp32 accumulate).
// B=4, T=4096, D=64, MASK_NUM=64.
// Grid: 256 blocks x 256 threads (1 block/CU). Block = 64 queries [tB,tB+64);
// union band = 192 keys [tB-64, tB+128) staged in LDS once:
//   Ks[192][72] bf16 row-major, d-chunk XOR swizzle (d' = d ^ ((u&3)<<3))
//   Vs[64][264] bf16 TRANSPOSED (V^T), k XOR-rotation swizzle (k' = k ^ (s(d)<<3))
// R11: staging rebuilt for latency-hiding (T14 issue-early/write-late):
//   - ALL global loads (mask, Q, K, V) issued first into statically-indexed
//     register arrays (~28 loads in flight, one HBM-latency exposure),
//     then converted + written to LDS.
//   - V loads vectorized: 12 float4/lane (paired keys, same 4 dims) instead
//     of 48 scalar dwords; V^T LDS writes pair two keys per ds_write_b32
//     (XOR swizzle keeps even pairs adjacent: sw<<3 never touches bit 0).
// Wave w handles 16 queries [tw, tw+16), key window = block rows [16w, 16w+144)
// (PV pads to 160 with zero-weight keys; the V^T tail [192,264) of each LDS
// row is ZEROED — R9 lesson: stale LDS there was Inf/NaN and 0 x Inf = NaN).
// QK^T: S^T = K·Q^T via mfma_f32_16x16x32_bf16 (A=K-tile from LDS, B=Q^T).
// D layout (HW-verified, validated end-to-end by R10 passing): col = lane&15
// = query, row = 4*(lane>>4)+reg = key -> softmax lane-local over 36 regs +
// shfl_xor(16,32).
// PV: O^T = V^T·P^T (A=V^T b128 reads, B=P^T built by shfl redistribution).
// Generic mask semantics preserved via block-uniform fallback.

typedef __attribute__((ext_vector_type(8))) short bf16x8;
typedef __attribute__((ext_vector_type(4))) float f32x4;

constexpr int kT    = 4096;
constexpr int kD    = 64;
constexpr int kBand = 64;   // MASK_NUM
constexpr int KP    = 72;   // K LDS pitch (bf16 elems), 144 B rows (16B-aligned)
constexpr int VP    = 264;  // V^T LDS pitch (bf16 elems), 528 B rows (16B-aligned)

__device__ __forceinline__ short f2bf(float x) {
    // fast round-to-nearest-ish f32 -> bf16 (inputs are tame: N(0,1)-scale)
    return (short)((__float_as_uint(x) + 0x8000u) >> 16);
}
__device__ __forceinline__ unsigned pack2(float lo, float hi) {
    return (unsigned)(unsigned short)f2bf(lo) |
           ((unsigned)(unsigned short)f2bf(hi) << 16);
}

__global__ __launch_bounds__(256, 1) void mfma_band_attn(
    const float* __restrict__ Q,
    const float* __restrict__ K,
    const float* __restrict__ V,
    const int*   __restrict__ M,
    float* __restrict__ O)
{
    __shared__ short Ks[192 * KP];
    __shared__ short Vs[64 * VP];
    __shared__ int   wflag[4];

    const int tid  = threadIdx.x;
    const int lane = tid & 63;
    const int wid  = tid >> 6;
    const int blk  = blockIdx.x;          // 256 blocks
    const int b    = blk >> 6;            // 64 query-blocks per batch
    const int tB   = (blk & 63) << 6;     // block's first query
    const int tw   = tB + 16 * wid;       // wave's first query
    const int h    = lane >> 4;           // 0..3
    const int q    = lane & 15;           // query col (B/D role) / key row (A role)

    const float* Qg = Q + (size_t)b * kT * kD;
    const float* Kg = K + (size_t)b * kT * kD;
    const float* Vg = V + (size_t)b * kT * kD;
    const int*   mb = M + b * kT;

    // ================= issue ALL global loads first (T14) =================
    // ---- mask probes ----
    int mk_win = 1, mk_q = 1;
    {
        int ka = tB - 64 + tid;
        if (tid < 192 && (unsigned)ka < (unsigned)kT) mk_win = mb[ka];
        if (tid < 64) mk_q = mb[tB + tid];
    }
    // ---- Q rows ----
    float4 qa0, qa1, qb0, qb1;
    {
        const float* qp = Qg + (size_t)(tw + q) * kD + 8 * h;
        qa0 = *(const float4*)(qp + 0);
        qa1 = *(const float4*)(qp + 4);
        qb0 = *(const float4*)(qp + 32);
        qb1 = *(const float4*)(qp + 36);
    }
    // ---- K tile: 12 float4/lane into registers ----
    float4 kreg[12];
    #pragma unroll
    for (int i = 0; i < 12; ++i) {
        const int idx = i * 256 + tid;          // 0..3071
        const int u   = idx >> 4;
        const int dc  = (idx & 15) << 2;
        int ka = tB - 64 + u;
        ka = ka < 0 ? 0 : (ka > kT - 1 ? kT - 1 : ka);
        kreg[i] = *(const float4*)(Kg + (size_t)ka * kD + dc);
    }
    // ---- V tile: paired-key float4 loads, 12/lane ----
    // wave stages keys [48w, 48w+48); lane a=lane>>4 picks the pair slot,
    // c=lane&15 picks dims 4c..4c+3; iter i covers keys 8i+2a, 8i+2a+1.
    const int va_ = lane >> 4;
    const int vc_ = lane & 15;
    float4 vA[6], vB[6];
    #pragma unroll
    for (int i = 0; i < 6; ++i) {
        const int u = 48 * wid + 8 * i + 2 * va_;
        int ka0 = tB - 64 + u;
        int ka1 = ka0 + 1;
        ka0 = ka0 < 0 ? 0 : (ka0 > kT - 1 ? kT - 1 : ka0);
        ka1 = ka1 < 0 ? 0 : (ka1 > kT - 1 ? kT - 1 : ka1);
        vA[i] = *(const float4*)(Vg + (size_t)ka0 * kD + 4 * vc_);
        vB[i] = *(const float4*)(Vg + (size_t)ka1 * kD + 4 * vc_);
    }

    // ================= convert + write (loads drain underneath) =================
    // ---- fast-path flag ----
    int ok = (mk_win && mk_q) ? 1 : 0;
    ok = __all(ok);
    if (lane == 0) wflag[wid] = ok;

    // ---- Q fragments (B-operand of QK): lane (h,q) holds Q[tw+q][..]*0.125 ----
    bf16x8 qf0, qf1;
    qf0[0] = f2bf(qa0.x * 0.125f); qf0[1] = f2bf(qa0.y * 0.125f);
    qf0[2] = f2bf(qa0.z * 0.125f); qf0[3] = f2bf(qa0.w * 0.125f);
    qf0[4] = f2bf(qa1.x * 0.125f); qf0[5] = f2bf(qa1.y * 0.125f);
    qf0[6] = f2bf(qa1.z * 0.125f); qf0[7] = f2bf(qa1.w * 0.125f);
    qf1[0] = f2bf(qb0.x * 0.125f); qf1[1] = f2bf(qb0.y * 0.125f);
    qf1[2] = f2bf(qb0.z * 0.125f); qf1[3] = f2bf(qb0.w * 0.125f);
    qf1[4] = f2bf(qb1.x * 0.125f); qf1[5] = f2bf(qb1.y * 0.125f);
    qf1[6] = f2bf(qb1.z * 0.125f); qf1[7] = f2bf(qb1.w * 0.125f);

    // ---- K -> LDS (row-major bf16, swizzled) ----
    #pragma unroll
    for (int i = 0; i < 12; ++i) {
        const int idx = i * 256 + tid;
        const int u   = idx >> 4;
        const int dc  = (idx & 15) << 2;
        const float4 f = kreg[i];
        *(uint2*)&Ks[u * KP + (dc ^ ((u & 3) << 3))] =
            make_uint2(pack2(f.x, f.y), pack2(f.z, f.w));
    }
    // ---- V -> LDS transposed (V^T[d][k], swizzled), paired b32 writes ----
    #pragma unroll
    for (int i = 0; i < 6; ++i) {
        const int u = 48 * wid + 8 * i + 2 * va_;   // even
        #pragma unroll
        for (int t = 0; t < 4; ++t) {
            const int dd = 4 * vc_ + t;
            const int sw = (dd + (dd >> 3)) & 7;
            const int pos = u ^ (sw << 3);          // even (sw<<3 keeps bit 0)
            const float lo = (t == 0) ? vA[i].x : (t == 1) ? vA[i].y
                           : (t == 2) ? vA[i].z : vA[i].w;
            const float hi = (t == 0) ? vB[i].x : (t == 1) ? vB[i].y
                           : (t == 2) ? vB[i].z : vB[i].w;
            *(unsigned int*)&Vs[dd * VP + pos] = pack2(lo, hi);
        }
    }
    // ---- zero the V^T tail [192, 264) of every row (R9 NaN fix) ----
    #pragma unroll
    for (int i = 0; i < 9; ++i) {
        const int idx = i * 256 + tid;          // 0..2303
        const int row = idx / 36;
        const int col = idx - row * 36;         // 36 uints = 72 shorts
        *(unsigned int*)&Vs[row * VP + 192 + 2 * col] = 0u;
    }
    __syncthreads();

    if (wflag[0] && wflag[1] && wflag[2] && wflag[3]) {
        // ================= fast path (MFMA) =================
        // acc[t][r] = score(key kk = 16t+4h+r (wave-local), query q); acc[9] = 0 pad
        f32x4 acc[10];
        #pragma unroll
        for (int t = 0; t < 10; ++t) acc[t] = (f32x4){0.f, 0.f, 0.f, 0.f};

        // QK^T: A = K-tile (m=key=lane&15, k=d), B = Q^T (n=q, k=d)
        #pragma unroll
        for (int t = 0; t < 9; ++t) {
            const int u  = 16 * wid + 16 * t + q;       // LDS K row (lane&15 = key)
            const short* kr = &Ks[u * KP];
            const int x  = (u & 3) << 3;
            const bf16x8 ka0 = *(const bf16x8*)(kr + ((8 * h) ^ x));
            const bf16x8 ka1 = *(const bf16x8*)(kr + ((32 + 8 * h) ^ x));
            acc[t] = __builtin_amdgcn_mfma_f32_16x16x32_bf16(ka0, qf0, acc[t], 0, 0, 0);
            acc[t] = __builtin_amdgcn_mfma_f32_16x16x32_bf16(ka1, qf1, acc[t], 0, 0, 0);
        }

        // ---- mask + softmax (lane-local over 36 scores, then shfl 16/32) ----
        const int base = tB - 64 + 16 * wid;  // absolute key of wave-local kk=0
        float mx = -1e30f;
        #pragma unroll
        for (int t = 0; t < 9; ++t) {
            #pragma unroll
            for (int r = 0; r < 4; ++r) {
                const int kk = 16 * t + 4 * h + r;
                const int ka = base + kk;
                const bool val = ((unsigned)(kk - q) <= 2u * kBand) &&
                                 ((unsigned)ka < (unsigned)kT);
                const float sc = val ? acc[t][r] : -1e30f;
                acc[t][r] = sc;
                mx = fmaxf(mx, sc);
            }
        }
        mx = fmaxf(mx, __shfl_xor(mx, 16, 64));
        mx = fmaxf(mx, __shfl_xor(mx, 32, 64));
        float lsum = 0.f;
        #pragma unroll
        for (int t = 0; t < 9; ++t) {
            #pragma unroll
            for (int r = 0; r < 4; ++r) {
                const float w = __expf(acc[t][r] - mx);   // exp(-1e30)=0 masked
                acc[t][r] = w;
                lsum += w;
            }
        }
        lsum += __shfl_xor(lsum, 16, 64);
        lsum += __shfl_xor(lsum, 32, 64);

        // ---- PV: O^T = V^T · P^T ----
        f32x4 oacc[4];
        #pragma unroll
        for (int dt = 0; dt < 4; ++dt) oacc[dt] = (f32x4){0.f, 0.f, 0.f, 0.f};

        #pragma unroll
        for (int ks = 0; ks < 5; ++ks) {
            // B-frag (P^T): lane (h,q) element j = P[key 32ks+8h+j][q]
            bf16x8 pf;
            #pragma unroll
            for (int j = 0; j < 8; ++j) {
                const int srcl = 16 * (2 * (h & 1) + (j >> 2)) + q;
                const float vlo = __shfl(acc[2 * ks][j & 3], srcl, 64);
                const float vhi = __shfl(acc[2 * ks + 1][j & 3], srcl, 64);
                pf[j] = f2bf((h < 2) ? vlo : vhi);
            }
            // A-frags (V^T): lane (h, d=16dt+q): keys u0..u0+7 of that d-row
            #pragma unroll
            for (int dt = 0; dt < 4; ++dt) {
                const int d  = 16 * dt + q;
                const int sw = (d + (d >> 3)) & 7;
                const int u0 = (16 * wid + 32 * ks + 8 * h) ^ (sw << 3);
                const bf16x8 vf = *(const bf16x8*)&Vs[d * VP + u0];
                oacc[dt] = __builtin_amdgcn_mfma_f32_16x16x32_bf16(vf, pf, oacc[dt], 0, 0, 0);
            }
        }

        // ---- write O: lane (h,q) holds O[tw+q][16dt+4h+reg] ----
        const float inv = 1.0f / lsum;
        float* Ob = O + (size_t)(b * kT + tw + q) * kD;
        #pragma unroll
        for (int dt = 0; dt < 4; ++dt) {
            float4 o;
            o.x = oacc[dt][0] * inv; o.y = oacc[dt][1] * inv;
            o.z = oacc[dt][2] * inv; o.w = oacc[dt][3] * inv;
            *(float4*)(Ob + 16 * dt + 4 * h) = o;
        }
        return;
    }

    // ================= generic fallback (mask not all-ones; cold) =================
    const int g8 = lane >> 3;
    const int r8 = lane & 7;
    for (int qq = 0; qq < 16; ++qq) {
        const int t  = tw + qq;
        const int qm = mb[t];
        const float* qp = Qg + (size_t)t * kD + 8 * r8;
        float4 q0 = *(const float4*)qp;
        float4 q1 = *(const float4*)(qp + 4);
        q0.x *= 0.125f; q0.y *= 0.125f; q0.z *= 0.125f; q0.w *= 0.125f;
        q1.x *= 0.125f; q1.y *= 0.125f; q1.z *= 0.125f; q1.w *= 0.125f;
        int lo, hi;
        if (qm) {
            lo = t - kBand; if (lo < 0) lo = 0;
            hi = t + kBand; if (hi > kT - 1) hi = kT - 1;
        } else {
            lo = 0; hi = kT - 1;
        }
        float m = -1e30f, l = 0.f;
        float4 a0 = make_float4(0.f, 0.f, 0.f, 0.f), a1 = a0;
        for (int s = lo + g8; s <= hi; s += 8) {
            const float* kr = Kg + (size_t)s * kD + 8 * r8;
            const float4 k0 = *(const float4*)kr;
            const float4 k1 = *(const float4*)(kr + 4);
            float d = q0.x * k0.x + q0.y * k0.y + q0.z * k0.z + q0.w * k0.w
                    + q1.x * k1.x + q1.y * k1.y + q1.z * k1.z + q1.w * k1.w;
            d += __shfl_xor(d, 1, 64);
            d += __shfl_xor(d, 2, 64);
            d += __shfl_xor(d, 4, 64);
            if (mb[s]) {
                if (d > m) {
                    const float scl = __expf(m - d);
                    l *= scl;
                    a0.x *= scl; a0.y *= scl; a0.z *= scl; a0.w *= scl;
                    a1.x *= scl; a1.y *= scl; a1.z *= scl; a1.w *= scl;
                    m = d;
                }
                const float w = __expf(d - m);
                const float* vr = Vg + (size_t)s * kD + 8 * r8;
                const float4 v0 = *(const float4*)vr;
                const float4 v1 = *(const float4*)(vr + 4);
                l += w;
                a0.x += w * v0.x; a0.y += w * v0.y; a0.z += w * v0.z; a0.w += w * v0.w;
                a1.x += w * v1.x; a1.y += w * v1.y; a1.z += w * v1.z; a1.w += w * v1.w;
            }
        }
        float Mx = m;
        Mx = fmaxf(Mx, __shfl_xor(Mx, 8, 64));
        Mx = fmaxf(Mx, __shfl_xor(Mx, 16, 64));
        Mx = fmaxf(Mx, __shfl_xor(Mx, 32, 64));
        const float scl = __expf(m - Mx);
        l *= scl;
        a0.x *= scl; a0.y *= scl; a0.z *= scl; a0.w *= scl;
        a1.x *= scl; a1.y *= scl; a1.z *= scl; a1.w *= scl;
        #pragma unroll
        for (int off = 8; off <= 32; off <<= 1) {
            l += __shfl_xor(l, off, 64);
            a0.x += __shfl_xor(a0.x, off, 64); a0.y += __shfl_xor(a0.y, off, 64);
            a0.z += __shfl_xor(a0.z, off, 64); a0.w += __shfl_xor(a0.w, off, 64);
            a1.x += __shfl_xor(a1.x, off, 64); a1.y += __shfl_xor(a1.y, off, 64);
            a1.z += __shfl_xor(a1.z, off, 64); a1.w += __shfl_xor(a1.w, off, 64);
        }
        if (g8 == 0) {
            const float inv = 1.0f / l;
            float* orow = O + (size_t)(b * kT + t) * kD + 8 * r8;
            float4 o0, o1;
            o0.x = a0.x * inv; o0.y = a0.y * inv; o0.z = a0.z * inv; o0.w = a0.w * inv;
            o1.x = a1.x * inv; o1.y = a1.y * inv; o1.z = a1.z * inv; o1.w = a1.w * inv;
            *(float4*)orow       = o0;
            *(float4*)(orow + 4) = o1;
        }
    }
}

extern "C" void kernel_launch(void* const* d_in, const int* in_sizes, int n_in,
                              void* d_out, int out_size, void* d_ws, size_t ws_size,
                              hipStream_t stream) {
    const float* q    = (const float*)d_in[0];
    const float* k    = (const float*)d_in[1];
    const float* v    = (const float*)d_in[2];
    const int*   mask = (const int*)d_in[3];
    float*       out  = (float*)d_out;
    (void)d_ws; (void)ws_size; (void)in_sizes; (void)n_in; (void)out_size;

    dim3 grid(256);    // 4 batches x 64 query-blocks, 64 queries each
    dim3 block(256);
    mfma_band_attn<<<grid, block, 0, stream>>>(q, k, v, mask, out);
}